// Round 6
// baseline (132.455 us; speedup 1.0000x reference)
//
#include <hip/hip_runtime.h>

// Embeder: out[b,t,:] = W[x[b,t]] + (x[b,t] not end AND exists end at t'>t)
//                        ? 1.5*W[nearest-future-end-symbol] : 0
// Dtypes: weight f32 [256,512], x int32 [B,T], end_ids int32 [2], out f32 [B,T,D].

typedef float f4 __attribute__((ext_vector_type(4)));

constexpr int TT = 1024;     // T
constexpr int DD = 512;      // D
constexpr int C4 = DD / 4;   // 128 float4 chunks per D-row
constexpr int NW = TT / 64;  // 16 waves per code-block

// ---- K1: per-token code = sym | (sel<<16); sel: 0=none, 1=+1.5W[e0], 2=+1.5W[e1] ----
__global__ __launch_bounds__(1024) void codes_kernel(
    const int* __restrict__ x,
    const int* __restrict__ end_ids,
    int* __restrict__ codes)
{
    __shared__ int wmin[NW];
    const int b    = blockIdx.x;
    const int tid  = threadIdx.x;
    const int wid  = tid >> 6;
    const int lane = tid & 63;
    const int e0 = end_ids[0], e1 = end_ids[1];
    const int INF = 0x7FFFFFFF;

    int sym = x[b * TT + tid];
    bool is_end = (sym == e0) || (sym == e1);
    int v = is_end ? ((tid << 1) | (sym == e0 ? 0 : 1)) : INF;

    #pragma unroll
    for (int off = 1; off < 64; off <<= 1) {
        int u = __shfl_down(v, off);
        v = (lane + off < 64) ? min(v, u) : v;
    }
    if (lane == 0) wmin[wid] = v;
    __syncthreads();

    int tailMin = INF;
    for (int w = wid + 1; w < NW; ++w) tailMin = min(tailMin, wmin[w]);

    int nvWave = __shfl_down(v, 1);
    int nv = (lane < 63) ? min(nvWave, tailMin) : tailMin;

    int sel = 0;
    if (!is_end && nv != INF) sel = (nv & 1) + 1;
    codes[b * TT + tid] = sym | (sel << 16);
}

// ---- K2: pure streamer. 256-thread blocks, grid-stride, no LDS/barriers ----
constexpr int BLK  = 256;
constexpr int GRID = 2048;                 // 8 blocks/CU
constexpr int NTH  = BLK * GRID;           // 524288 threads (multiple of 128)

__global__ __launch_bounds__(BLK) void stream_kernel(
    const float* __restrict__ weight,
    const int* __restrict__ codes,
    const int* __restrict__ end_ids,
    float* __restrict__ out,
    int total_c4)                          // B*T*C4 f4-chunks
{
    const int tid  = threadIdx.x;
    const int base = blockIdx.x * BLK + tid;
    const int c4   = base & 127;           // invariant across grid-stride iters
    const int e0 = end_ids[0], e1 = end_ids[1];

    const f4* wv = (const f4*)weight;
    f4 ea = wv[e0 * C4 + c4] * 1.5f;       // pre-scaled end rows, registers
    f4 eb = wv[e1 * C4 + c4] * 1.5f;
    f4* ov = (f4*)out;

    const int iters = total_c4 / NTH;      // 64
    #pragma unroll 8
    for (int i = 0; i < iters; ++i) {
        int idx = base + i * NTH;
        int t   = idx >> 7;                // wave-uniform global token index
        int c   = codes[t];                // L2-resident (1 MB), broadcast
        int symt = c & 0xFFFF;
        int selt = c >> 16;
        f4 wq = wv[symt * C4 + c4];
        if (selt) {
            f4 e = (selt == 1) ? ea : eb;  // wave-uniform, registers only
            wq += e;
        }
        __builtin_nontemporal_store(wq, &ov[idx]);
    }
}

extern "C" void kernel_launch(void* const* d_in, const int* in_sizes, int n_in,
                              void* d_out, int out_size, void* d_ws, size_t ws_size,
                              hipStream_t stream) {
    const float* weight  = (const float*)d_in[0];
    const int*   x       = (const int*)d_in[1];
    const int*   end_ids = (const int*)d_in[2];
    float*       out     = (float*)d_out;
    int*         codes   = (int*)d_ws;     // B*T ints = 1 MB scratch

    const int B = in_sizes[1] / TT;        // 256
    codes_kernel<<<B, 1024, 0, stream>>>(x, end_ids, codes);
    const int total_c4 = B * TT * C4;      // 33.55M
    stream_kernel<<<GRID, BLK, 0, stream>>>(weight, codes, end_ids, out, total_c4);
}

// Round 7
// 112.580 us; speedup vs baseline: 1.1765x; 1.1765x over previous
//
#include <hip/hip_runtime.h>

// Embeder: out[b,t,:] = W[x[b,t]] + (x[b,t] not end AND exists end at t'>t)
//                        ? 1.5*W[nearest-future-end-symbol] : 0
// Dtypes: weight f32 [256,512], x int32 [B,T], end_ids int32 [2], out f32 [B,T,D].

typedef float f4 __attribute__((ext_vector_type(4)));

constexpr int TT = 1024;     // T
constexpr int DD = 512;      // D
constexpr int C4 = DD / 4;   // 128 f4 chunks per D-row
constexpr int NW = TT / 64;  // 16 waves per code-block

// ---- K1: per-token code = sym | (sel<<16); sel: 0=none, 1=+1.5W[e0], 2=+1.5W[e1] ----
__global__ __launch_bounds__(1024) void codes_kernel(
    const int* __restrict__ x,
    const int* __restrict__ end_ids,
    int* __restrict__ codes)
{
    __shared__ int wmin[NW];
    const int b    = blockIdx.x;
    const int tid  = threadIdx.x;
    const int wid  = tid >> 6;
    const int lane = tid & 63;
    const int e0 = end_ids[0], e1 = end_ids[1];
    const int INF = 0x7FFFFFFF;

    int sym = x[b * TT + tid];
    bool is_end = (sym == e0) || (sym == e1);
    int v = is_end ? ((tid << 1) | (sym == e0 ? 0 : 1)) : INF;

    #pragma unroll
    for (int off = 1; off < 64; off <<= 1) {
        int u = __shfl_down(v, off);
        v = (lane + off < 64) ? min(v, u) : v;
    }
    if (lane == 0) wmin[wid] = v;
    __syncthreads();

    int tailMin = INF;
    for (int w = wid + 1; w < NW; ++w) tailMin = min(tailMin, wmin[w]);

    int nvWave = __shfl_down(v, 1);
    int nv = (lane < 63) ? min(nvWave, tailMin) : tailMin;

    int sel = 0;
    if (!is_end && nv != INF) sel = (nv & 1) + 1;
    codes[b * TT + tid] = sym | (sel << 16);
}

// ---- K2: pure streamer, CONTIGUOUS 64KB slab per block ----
constexpr int BLK   = 256;
constexpr int IT    = 16;              // iters per thread
constexpr int CHUNK = BLK * IT;        // 4096 f4 = 64 KB per block

__global__ __launch_bounds__(BLK) void stream_kernel(
    const float* __restrict__ weight,
    const int* __restrict__ codes,
    const int* __restrict__ end_ids,
    float* __restrict__ out)
{
    const int tid = threadIdx.x;
    const int bid = blockIdx.x;
    const int c4  = tid & 127;         // lane's chunk within a D-row (invariant)
    const int e0 = end_ids[0], e1 = end_ids[1];

    const f4* wv = (const f4*)weight;
    f4 ea = wv[e0 * C4 + c4] * 1.5f;   // pre-scaled end rows in registers
    f4 eb = wv[e1 * C4 + c4] * 1.5f;
    f4* ov = (f4*)out;

    const int base  = bid * CHUNK + tid;
    const int tbase = bid * (CHUNK / C4) + (tid >> 7);   // token idx base

    #pragma unroll 8
    for (int k = 0; k < IT; ++k) {
        int idx = base + k * BLK;
        int t   = tbase + k * 2;       // wave-uniform token index
        int c   = codes[t];            // L2-resident (1 MB), broadcast
        int symt = c & 0xFFFF;
        int selt = c >> 16;
        f4 wq = wv[symt * C4 + c4];
        if (selt) {
            f4 e = (selt == 1) ? ea : eb;   // wave-uniform, registers only
            wq += e;
        }
        __builtin_nontemporal_store(wq, &ov[idx]);
    }
}

extern "C" void kernel_launch(void* const* d_in, const int* in_sizes, int n_in,
                              void* d_out, int out_size, void* d_ws, size_t ws_size,
                              hipStream_t stream) {
    const float* weight  = (const float*)d_in[0];
    const int*   x       = (const int*)d_in[1];
    const int*   end_ids = (const int*)d_in[2];
    float*       out     = (float*)d_out;
    int*         codes   = (int*)d_ws;     // B*T ints = 1 MB scratch

    const int B = in_sizes[1] / TT;        // 256
    codes_kernel<<<B, 1024, 0, stream>>>(x, end_ids, codes);
    const int total_c4 = B * TT * C4;      // 33.55M f4 chunks
    stream_kernel<<<total_c4 / CHUNK, BLK, 0, stream>>>(weight, codes, end_ids, out);
}

// Round 8
// 93.022 us; speedup vs baseline: 1.4239x; 1.2103x over previous
//
#include <hip/hip_runtime.h>

// Embeder: out[b,t,:] = W[x[b,t]] + (x[b,t] not end AND exists end at t'>t)
//                        ? 1.5*W[nearest-future-end-symbol] : 0
// Dtypes: weight f32 [256,512], x int32 [B,T], end_ids int32 [2], out f32 [B,T,D].

typedef float f4 __attribute__((ext_vector_type(4)));

constexpr int TT = 1024;     // T
constexpr int DD = 512;      // D
constexpr int C4 = DD / 4;   // 128 f4 chunks per D-row
constexpr int SPLIT = 2;     // 2 blocks per row -> 1 MB contiguous slab per block
constexpr int NW = TT / 64;  // 16 waves per block

__global__ __launch_bounds__(1024) void embeder_kernel(
    const float* __restrict__ weight,
    const int* __restrict__ x,
    const int* __restrict__ end_ids,
    float* __restrict__ out)
{
    __shared__ int wmin[NW];  // per-wave suffix-min totals
    __shared__ int code[TT];  // sym | (sel<<16); sel: 0=none, 1=e0, 2=e1

    const int b    = blockIdx.x / SPLIT;
    const int sp   = blockIdx.x % SPLIT;
    const int tid  = threadIdx.x;
    const int wid  = tid >> 6;
    const int lane = tid & 63;
    const int e0 = end_ids[0], e1 = end_ids[1];
    const int INF = 0x7FFFFFFF;

    // ---- hoisted: this lane's end-row chunks (loop-invariant), pre-scaled by 1.5 ----
    const int c4 = tid & 127;
    const f4* wv = (const f4*)weight;
    f4 ea = wv[e0 * C4 + c4] * 1.5f;
    f4 eb = wv[e1 * C4 + c4] * 1.5f;

    // ---- phase 1: nearest-future-end via shuffle-based suffix-min (2 barriers) ----
    int sym = x[b * TT + tid];
    bool is_end = (sym == e0) || (sym == e1);
    int v = is_end ? ((tid << 1) | (sym == e0 ? 0 : 1)) : INF;

    #pragma unroll
    for (int off = 1; off < 64; off <<= 1) {
        int u = __shfl_down(v, off);
        v = (lane + off < 64) ? min(v, u) : v;
    }
    if (lane == 0) wmin[wid] = v;   // whole-wave min
    __syncthreads();

    int tailMin = INF;
    for (int w = wid + 1; w < NW; ++w) tailMin = min(tailMin, wmin[w]);

    int nvWave = __shfl_down(v, 1);
    int nv = (lane < 63) ? min(nvWave, tailMin) : tailMin;

    int sel = 0;
    if (!is_end && nv != INF) sel = (nv & 1) + 1; // 1 -> +1.5*W[e0], 2 -> +1.5*W[e1]
    code[tid] = sym | (sel << 16);
    __syncthreads();

    // ---- phase 2: streaming write, 1 MB contiguous slab per block ----
    f4* ov = (f4*)out + (size_t)b * TT * C4;

    const int iters = (TT * C4) / 1024 / SPLIT;   // 64
    const int kbase = sp * iters;
    #pragma unroll 8
    for (int k = 0; k < iters; ++k) {
        int idx = tid + (kbase + k) * 1024;
        int t   = idx >> 7;          // wave-uniform
        int c    = code[t];          // LDS broadcast within wave
        int symt = c & 0xFFFF;
        int selt = c >> 16;
        f4 wq = wv[symt * C4 + c4];
        if (selt) {
            f4 e = (selt == 1) ? ea : eb;   // wave-uniform select, registers only
            wq += e;
        }
        __builtin_nontemporal_store(wq, &ov[idx]);
    }
}

extern "C" void kernel_launch(void* const* d_in, const int* in_sizes, int n_in,
                              void* d_out, int out_size, void* d_ws, size_t ws_size,
                              hipStream_t stream) {
    const float* weight  = (const float*)d_in[0];
    const int*   x       = (const int*)d_in[1];
    const int*   end_ids = (const int*)d_in[2];
    float*       out     = (float*)d_out;

    const int B = in_sizes[1] / TT;   // 256
    embeder_kernel<<<B * SPLIT, 1024, 0, stream>>>(weight, x, end_ids, out);
}

// Round 9
// 91.026 us; speedup vs baseline: 1.4551x; 1.0219x over previous
//
#include <hip/hip_runtime.h>

// Embeder: out[b,t,:] = W[x[b,t]] + (x[b,t] not end AND exists end at t'>t)
//                        ? 1.5*W[nearest-future-end-symbol] : 0
// Dtypes: weight f32 [256,512], x int32 [B,T], end_ids int32 [2], out f32 [B,T,D].

typedef float f4 __attribute__((ext_vector_type(4)));

constexpr int TT = 1024;     // T
constexpr int DD = 512;      // D
constexpr int C4 = DD / 4;   // 128 f4 chunks per D-row
constexpr int NW = TT / 64;  // 16 waves per block

__global__ __launch_bounds__(1024) void embeder_kernel(
    const float* __restrict__ weight,
    const int* __restrict__ x,
    const int* __restrict__ end_ids,
    float* __restrict__ out)
{
    __shared__ int wmin[NW];  // per-wave suffix-min totals
    __shared__ int code[TT];  // sym | (sel<<16); sel: 0=none, 1=e0, 2=e1

    const int b    = blockIdx.x;        // one block per row: 2 MB contiguous stream
    const int tid  = threadIdx.x;
    const int wid  = tid >> 6;
    const int lane = tid & 63;
    const int e0 = end_ids[0], e1 = end_ids[1];
    const int INF = 0x7FFFFFFF;

    // ---- hoisted: this lane's end-row chunks (loop-invariant), pre-scaled by 1.5 ----
    const int c4 = tid & 127;
    const f4* wv = (const f4*)weight;
    f4 ea = wv[e0 * C4 + c4] * 1.5f;
    f4 eb = wv[e1 * C4 + c4] * 1.5f;

    // ---- phase 1: nearest-future-end via shuffle-based suffix-min (2 barriers) ----
    int sym = x[b * TT + tid];
    bool is_end = (sym == e0) || (sym == e1);
    int v = is_end ? ((tid << 1) | (sym == e0 ? 0 : 1)) : INF;

    #pragma unroll
    for (int off = 1; off < 64; off <<= 1) {
        int u = __shfl_down(v, off);
        v = (lane + off < 64) ? min(v, u) : v;
    }
    if (lane == 0) wmin[wid] = v;   // whole-wave min
    __syncthreads();

    int tailMin = INF;
    for (int w = wid + 1; w < NW; ++w) tailMin = min(tailMin, wmin[w]);

    int nvWave = __shfl_down(v, 1);
    int nv = (lane < 63) ? min(nvWave, tailMin) : tailMin;

    int sel = 0;
    if (!is_end && nv != INF) sel = (nv & 1) + 1; // 1 -> +1.5*W[e0], 2 -> +1.5*W[e1]
    code[tid] = sym | (sel << 16);
    __syncthreads();

    // ---- phase 2: streaming write, 2 MB contiguous slab per block ----
    f4* ov = (f4*)out + (size_t)b * TT * C4;

    const int iters = (TT * C4) / 1024;   // 128
    #pragma unroll 8
    for (int k = 0; k < iters; ++k) {
        int idx = tid + k * 1024;
        int t   = idx >> 7;          // wave-uniform
        int c    = code[t];          // LDS broadcast within wave
        int symt = c & 0xFFFF;
        int selt = c >> 16;
        f4 wq = wv[symt * C4 + c4];
        if (selt) {
            f4 e = (selt == 1) ? ea : eb;   // wave-uniform select, registers only
            wq += e;
        }
        __builtin_nontemporal_store(wq, &ov[idx]);
    }
}

extern "C" void kernel_launch(void* const* d_in, const int* in_sizes, int n_in,
                              void* d_out, int out_size, void* d_ws, size_t ws_size,
                              hipStream_t stream) {
    const float* weight  = (const float*)d_in[0];
    const int*   x       = (const int*)d_in[1];
    const int*   end_ids = (const int*)d_in[2];
    float*       out     = (float*)d_out;

    const int B = in_sizes[1] / TT;   // 256
    embeder_kernel<<<B, 1024, 0, stream>>>(weight, x, end_ids, out);
}